// Round 14
// baseline (550.978 us; speedup 1.0000x reference)
//
#include <hip/hip_runtime.h>

#define N_PTS 131072
#define TILE 64
#define THREADS 512
#define REGION 40960   // per-head perm region (counts ~32.8K, >40 sigma headroom)

typedef __bf16 bf16;
typedef __bf16 bf16x8 __attribute__((ext_vector_type(8)));
typedef float f32x4 __attribute__((ext_vector_type(4)));

// ---------------- workspace layout (bytes) ----------------
#define WS_PERM_OFF   256                        // int perm[4][REGION]
#define WS_WPACK_OFF  (256 + 4 * REGION * 4)     // = 655616, bf16 packed weights
// packed-weight element offsets (bf16 elements, all [out][K] "transposed")
#define OFF_W0     0          // [256][64]   (k=63 zero pad)
#define OFF_WS     16384      // [3][256][256]
#define OFF_TW0    212992     // [4][256][320] (k: 0..62 pts, 63 zero, 64..319 h)
#define OFF_TWS    540672     // [12][256][256]
#define OFF_FEATW  1327104    // [4][256][256]
#define OFF_VIEWSW 1589248    // [4][128][288] (k: 0..255 feat, 256..282 views, 283..287 zero)
#define TOTAL_PACK 1736704

// ---------------- LDS layout (bytes) ----------------
// PTS [64][64]bf16 (8KB) + in-place H [64][256]bf16 (32KB)
// + B double-buffer 2 x 16KB = 72KB -> 2 blocks/CU.
#define PTS_BASE 0
#define H_BASE   8192
#define B_BASE   40960
#define LDS_BYTES 73728

__device__ __forceinline__ unsigned swz(unsigned base, unsigned row, unsigned rowstride,
                                        unsigned kbyte) {
  return (base + row * rowstride + kbyte) ^ ((row & 7u) << 4);
}

// async global->LDS, 16B per lane; LDS dest = wave-uniform base + lane*16
__device__ __forceinline__ void gload_lds16(const bf16* g, char* l) {
  __builtin_amdgcn_global_load_lds(
      (const __attribute__((address_space(1))) void*)g,
      (__attribute__((address_space(3))) void*)l, 16, 0, 0);
}

// ================= weight pack (fp32->bf16 transpose) + head scatter =================
// Bucketing folded in: per-head perm REGIONS with atomic cursors (ballot-
// aggregated, <=4 atomics/wave). No count/scan/scatter kernels -> launch
// chain is memset + k_pack + k_main (r13 lost ~86us to 3 extra launches).
// Order within a region is nondeterministic but rows are independent ->
// final output deterministic.
__global__ void k_pack(const float* __restrict__ W0, const float* __restrict__ Ws,
                       const float* __restrict__ tW0, const float* __restrict__ tWs,
                       const float* __restrict__ featW, const float* __restrict__ viewsW,
                       bf16* __restrict__ out, const int* __restrict__ head,
                       int* __restrict__ ctrl, int* __restrict__ perm) {
  int gid = blockIdx.x * blockDim.x + threadIdx.x;
  if (gid < N_PTS) {
    int h = head[gid];
    int lane = threadIdx.x & 63;
    #pragma unroll
    for (int hh = 0; hh < 4; ++hh) {
      unsigned long long m = __ballot(h == hh);
      if (m == 0ull) continue;
      int leader = __builtin_ctzll(m);
      int base = 0;
      if (lane == leader) base = atomicAdd(&ctrl[16 + hh], __popcll(m));
      base = __shfl(base, leader);
      if (h == hh) {
        int rank = __popcll(m & ((1ull << lane) - 1ull));
        perm[hh * REGION + base + rank] = gid;
      }
    }
  }

  for (int idx = gid; idx < TOTAL_PACK; idx += gridDim.x * blockDim.x) {
    float v;
    if (idx < OFF_WS) {
      int o = idx >> 6, k = idx & 63;
      v = (k < 63) ? W0[k * 256 + o] : 0.f;
    } else if (idx < OFF_TW0) {
      int i = idx - OFF_WS; int l = i >> 16, r = i & 65535, o = r >> 8, k = r & 255;
      v = Ws[l * 65536 + k * 256 + o];
    } else if (idx < OFF_TWS) {
      int i = idx - OFF_TW0; int h = i / 81920, r = i % 81920, o = r / 320, k = r % 320;
      v = (k < 63) ? tW0[(h * 319 + k) * 256 + o]
                   : (k == 63 ? 0.f : tW0[(h * 319 + k - 1) * 256 + o]);
    } else if (idx < OFF_FEATW) {
      int i = idx - OFF_TWS; int hj = i >> 16, r = i & 65535, o = r >> 8, k = r & 255;
      v = tWs[(hj * 256 + k) * 256 + o];
    } else if (idx < OFF_VIEWSW) {
      int i = idx - OFF_FEATW; int h = i >> 16, r = i & 65535, o = r >> 8, k = r & 255;
      v = featW[(h * 256 + k) * 256 + o];
    } else {
      int i = idx - OFF_VIEWSW; int h = i / 36864, r = i % 36864, o = r / 288, k = r % 288;
      v = (k < 283) ? viewsW[(h * 283 + k) * 128 + o] : 0.f;
    }
    out[idx] = (bf16)v;
  }
}

// ================= B tile staging (global_load_lds) =================
// Tile = B[o][kk..kk+32), o in [0,OUTS). 8 waves x (OUTS/128) 1KB regions.
// LDS slot (o,j) at byte o*64+j*16 holds global k-chunk (j ^ ((o>>1)&3));
// reader slot l4 ^ ((col>>1)&3) spreads 16 lanes over all 8 slots = 2-way
// (free); verified r12: conflicts 1.9e7 -> 9.6e6.
template <int OUTS>
__device__ __forceinline__ void stage_B(const bf16* __restrict__ Wt, int wK, int kk,
                                        char* lds, int bufsel, int wave, int lane) {
  constexpr int ISSUES = OUTS / 128;   // 2 (OUTS=256) or 1 (OUTS=128)
  #pragma unroll
  for (int s = 0; s < ISSUES; ++s) {
    int reg = wave * ISSUES + s;            // 1KB region index
    int o = reg * 16 + (lane >> 2);
    int j = lane & 3;
    const bf16* g = Wt + o * wK + kk + ((j ^ ((o >> 1) & 3)) << 3);
    gload_lds16(g, lds + B_BASE + bufsel * 16384 + reg * 1024);
  }
}

// ================= fused MLP layer (MFMA, pipelined LDS-staged B) =================
// 8 waves as 2 row-groups x 4 col-groups; wave tile = MR*16 x NF*16 (32x64).
// Per kc-step (T3 2-phase): vmcnt(0) [stage(kc), one phase of slack] ->
// s_barrier -> stage(kc+1) early -> ds_read A,B -> setprio(1) 8 MFMA setprio(0).
template <int MR, int NF, bool RELU, int A0KC, int A1KC, int OUTS>
__device__ __forceinline__ void mfma_layer(char* lds, const bf16* __restrict__ Wt, int wK,
                                           const float* __restrict__ bias,
                                           int a0_base, int a0_stride,
                                           int a1_base, int a1_stride,
                                           int out_base, int out_stride,
                                           int lane, int wave) {
  const int l15 = lane & 15, l4 = lane >> 4;
  const int wr = wave >> 2, wc = wave & 3;
  constexpr int KC = A0KC + A1KC;
  f32x4 acc[MR][NF];
  #pragma unroll
  for (int m = 0; m < MR; ++m)
    #pragma unroll
    for (int n = 0; n < NF; ++n) acc[m][n] = (f32x4){0.f, 0.f, 0.f, 0.f};

  const int r0 = wr * (MR * 16);
  const int c0 = wc * (NF * 16);

  stage_B<OUTS>(Wt, wK, 0, lds, 0, wave, lane);

  #pragma unroll 1
  for (int kc = 0; kc < KC; ++kc) {
    asm volatile("s_waitcnt vmcnt(0)" ::: "memory");  // stage(kc) landed
    __builtin_amdgcn_s_barrier();

    const int buf = kc & 1;
    if (kc + 1 < KC) stage_B<OUTS>(Wt, wK, (kc + 1) * 32, lds, buf ^ 1, wave, lane);

    const int base   = (kc < A0KC) ? a0_base   : a1_base;
    const int stride = (kc < A0KC) ? a0_stride : a1_stride;
    const int kl     = ((kc < A0KC) ? kc : kc - A0KC) * 32;
    bf16x8 a[MR];
    #pragma unroll
    for (int m = 0; m < MR; ++m)
      a[m] = *(const bf16x8*)(lds + swz(base, r0 + m * 16 + l15, stride,
                                        (kl + l4 * 8) * 2));
    bf16x8 b[NF];
    #pragma unroll
    for (int n = 0; n < NF; ++n) {
      int col = c0 + n * 16 + l15;
      b[n] = *(const bf16x8*)(lds + B_BASE + buf * 16384 + col * 64 +
                              ((l4 ^ ((col >> 1) & 3)) << 4));
    }

    __builtin_amdgcn_s_setprio(1);
    #pragma unroll
    for (int n = 0; n < NF; ++n)
      #pragma unroll
      for (int m = 0; m < MR; ++m)
        acc[m][n] = __builtin_amdgcn_mfma_f32_16x16x32_bf16(a[m], b[n], acc[m][n], 0, 0, 0);
    __builtin_amdgcn_s_setprio(0);
  }

  // all waves' A-reads complete (reads retire before their MFMAs, which
  // precede this barrier) -> in-place overwrite of the A region is safe
  __builtin_amdgcn_s_barrier();

  #pragma unroll
  for (int n = 0; n < NF; ++n) {
    int col = c0 + n * 16 + l15;
    float bv = bias[col];
    #pragma unroll
    for (int m = 0; m < MR; ++m) {
      #pragma unroll
      for (int j = 0; j < 4; ++j) {
        float v = acc[m][n][j] + bv;
        if (RELU) v = fmaxf(v, 0.f);
        int row = r0 + m * 16 + l4 * 4 + j;
        *(bf16*)(lds + swz(out_base, row, out_stride, col * 2)) = (bf16)v;
      }
    }
  }
  __syncthreads();  // full drain: epilogue visible to next layer
}

// ================= main fused kernel =================
// launch_bounds(512,2): budget 256 regs so the allocator is NOT squeezed
// into the 64-arch/64-acc split that spilled at (512,4) (r5/7/8/13 all
// pinned VGPR_Count=64 + ~57-102MB scratch). Actual demand ~100-124 (r11
// measured 124 with acc=64; this config's acc=32) -> <=128 regs -> the HW
// still co-schedules 2 blocks/CU = 4 waves/SIMD, now spill-free.
__global__ __launch_bounds__(THREADS, 2) void k_main(
    const float* __restrict__ x, const int* __restrict__ ctrl, const int* __restrict__ perm,
    const bf16* __restrict__ wpack,
    const float* __restrict__ b0, const float* __restrict__ bs,
    const float* __restrict__ tb0p, const float* __restrict__ tbsp,
    const float* __restrict__ featb, const float* __restrict__ alphaW,
    const float* __restrict__ alphab, const float* __restrict__ viewsb,
    const float* __restrict__ rgbW, const float* __restrict__ rgbb,
    float* __restrict__ outp) {
  __shared__ __attribute__((aligned(16))) char lds[LDS_BYTES];
  __shared__ int pidx[TILE];
  __shared__ float alpha_s[TILE];

  const int tid = threadIdx.x;
  const int lane = tid & 63, wave = tid >> 6;

  // ---- fixed-grid head/tile mapping: block -> (head, tile) ----
  const int hh = blockIdx.x / (REGION / TILE);
  const int start = (blockIdx.x % (REGION / TILE)) * TILE;
  const int cnt = ctrl[16 + hh];
  if (start >= cnt) return;            // empty tile (uniform exit)
  const int nv = min(TILE, cnt - start);

  if (tid < TILE) pidx[tid] = (tid < nv) ? perm[hh * REGION + start + tid] : -1;
  __syncthreads();

  // ---- pts -> LDS bf16 [64][64] (col 63 = 0, rows>=nv = 0) ----
  for (int i = tid; i < TILE * 64; i += THREADS) {
    int row = i >> 6, c = i & 63;
    int p = pidx[row];
    float v = (p >= 0 && c < 63) ? x[p * 90 + c] : 0.f;
    *(bf16*)(lds + swz(PTS_BASE, row, 128, c * 2)) = (bf16)v;
  }
  __syncthreads();  // pts visible before W0's raw-barrier loop reads them

  const bf16* W0p    = wpack + OFF_W0;
  const bf16* Wsp    = wpack + OFF_WS;
  const bf16* tW0p   = wpack + OFF_TW0 + hh * 81920;
  const bf16* tWsp   = wpack + OFF_TWS + hh * 3 * 65536;
  const bf16* featWp = wpack + OFF_FEATW + hh * 65536;
  const bf16* viewsWp= wpack + OFF_VIEWSW + hh * 36864;

  // trunk: 63->256, 3x 256->256 (in-place H)
  mfma_layer<2, 4, true, 2, 0, 256>(lds, W0p, 64, b0, PTS_BASE, 128, 0, 0, H_BASE, 512, lane, wave);
  mfma_layer<2, 4, true, 8, 0, 256>(lds, Wsp,          256, bs,       H_BASE, 512, 0, 0, H_BASE, 512, lane, wave);
  mfma_layer<2, 4, true, 8, 0, 256>(lds, Wsp + 65536,  256, bs + 256, H_BASE, 512, 0, 0, H_BASE, 512, lane, wave);
  mfma_layer<2, 4, true, 8, 0, 256>(lds, Wsp + 131072, 256, bs + 512, H_BASE, 512, 0, 0, H_BASE, 512, lane, wave);
  // T0: concat(pts, h) 320 -> 256
  mfma_layer<2, 4, true, 2, 8, 256>(lds, tW0p, 320, tb0p + hh * 256,
                                    PTS_BASE, 128, H_BASE, 512, H_BASE, 512, lane, wave);

  // views -> PTS cols 0..31 (T0's PTS reads complete before its epilogue barrier)
  for (int i = tid; i < TILE * 32; i += THREADS) {
    int row = i >> 5, c = i & 31;
    int p = pidx[row];
    float v = (p >= 0 && c < 27) ? x[p * 90 + 63 + c] : 0.f;
    *(bf16*)(lds + swz(PTS_BASE, row, 128, c * 2)) = (bf16)v;
  }
  __syncthreads();  // views-gather writes drained before later raw-barrier layers

  // head layers
  mfma_layer<2, 4, true, 8, 0, 256>(lds, tWsp,          256, tbsp + hh * 768,       H_BASE, 512, 0, 0, H_BASE, 512, lane, wave);
  mfma_layer<2, 4, true, 8, 0, 256>(lds, tWsp + 65536,  256, tbsp + hh * 768 + 256, H_BASE, 512, 0, 0, H_BASE, 512, lane, wave);
  mfma_layer<2, 4, true, 8, 0, 256>(lds, tWsp + 131072, 256, tbsp + hh * 768 + 512, H_BASE, 512, 0, 0, H_BASE, 512, lane, wave);

  // ---- alpha = ha . alphaW[hh] + alphab (waves 0-3; completes before feat's
  //      epilogue because all waves must pass feat's kc barriers first) ----
  if (wave < 4) {
    int p = wave * 16 + (lane & 15);
    int kq = lane >> 4;
    const float* aW = alphaW + hh * 256;
    float s = 0.f;
    for (int i = 0; i < 8; ++i) {
      int k = kq * 64 + i * 8;
      bf16x8 hv8 = *(const bf16x8*)(lds + swz(H_BASE, p, 512, k * 2));
      #pragma unroll
      for (int j = 0; j < 8; ++j) s += (float)hv8[j] * aW[k + j];
    }
    s += __shfl_xor(s, 16);
    s += __shfl_xor(s, 32);
    if (kq == 0) alpha_s[p] = s + alphab[hh];
  }

  // feat: 256->256 in-place, NO relu
  mfma_layer<2, 4, false, 8, 0, 256>(lds, featWp, 256, featb + hh * 256,
                                     H_BASE, 512, 0, 0, H_BASE, 512, lane, wave);
  // views: concat(feat, views[32pad]) 288 -> 128, relu, into H cols 0..127
  mfma_layer<2, 2, true, 8, 1, 128>(lds, viewsWp, 288, viewsb + hh * 128,
                                    H_BASE, 512, PTS_BASE, 128, H_BASE, 512, lane, wave);

  // ---- rgb = hv . rgbW[hh] + rgbb ; write float4 {r,g,b,alpha} (waves 0-3) ----
  if (wave < 4) {
    int p = wave * 16 + (lane & 15);
    int kq = lane >> 4;
    const float* rW = rgbW + hh * 128 * 3;
    float r0 = 0.f, r1 = 0.f, r2 = 0.f;
    for (int i = 0; i < 4; ++i) {
      int k = kq * 32 + i * 8;
      bf16x8 hv8 = *(const bf16x8*)(lds + swz(H_BASE, p, 512, k * 2));
      #pragma unroll
      for (int j = 0; j < 8; ++j) {
        float hvf = (float)hv8[j];
        r0 += hvf * rW[(k + j) * 3 + 0];
        r1 += hvf * rW[(k + j) * 3 + 1];
        r2 += hvf * rW[(k + j) * 3 + 2];
      }
    }
    r0 += __shfl_xor(r0, 16); r0 += __shfl_xor(r0, 32);
    r1 += __shfl_xor(r1, 16); r1 += __shfl_xor(r1, 32);
    r2 += __shfl_xor(r2, 16); r2 += __shfl_xor(r2, 32);
    if (kq == 0 && p < nv) {
      int pt = pidx[p];
      float4 o = make_float4(r0 + rgbb[hh * 3 + 0], r1 + rgbb[hh * 3 + 1],
                             r2 + rgbb[hh * 3 + 2], alpha_s[p]);
      *(float4*)(outp + pt * 4) = o;
    }
  }
}

// ================= launch =================
extern "C" void kernel_launch(void* const* d_in, const int* in_sizes, int n_in,
                              void* d_out, int out_size, void* d_ws, size_t ws_size,
                              hipStream_t stream) {
  const float* x      = (const float*)d_in[0];
  const int*   head   = (const int*)d_in[1];
  const float* W0     = (const float*)d_in[2];
  const float* b0     = (const float*)d_in[3];
  const float* Ws     = (const float*)d_in[4];
  const float* bs     = (const float*)d_in[5];
  const float* tW0    = (const float*)d_in[6];
  const float* tb0    = (const float*)d_in[7];
  const float* tWs    = (const float*)d_in[8];
  const float* tbs    = (const float*)d_in[9];
  const float* featW  = (const float*)d_in[10];
  const float* featb  = (const float*)d_in[11];
  const float* alphaW = (const float*)d_in[12];
  const float* alphab = (const float*)d_in[13];
  const float* viewsW = (const float*)d_in[14];
  const float* viewsb = (const float*)d_in[15];
  const float* rgbW   = (const float*)d_in[16];
  const float* rgbb   = (const float*)d_in[17];

  int*  ctrl  = (int*)d_ws;
  int*  perm  = (int*)((char*)d_ws + WS_PERM_OFF);
  bf16* wpack = (bf16*)((char*)d_ws + WS_WPACK_OFF);

  hipMemsetAsync(ctrl, 0, 256, stream);
  k_pack<<<2048, 256, 0, stream>>>(W0, Ws, tW0, tWs, featW, viewsW, wpack, head, ctrl, perm);
  k_main<<<4 * (REGION / TILE), THREADS, 0, stream>>>(x, ctrl, perm, wpack,
                                                      b0, bs, tb0, tbs, featb, alphaW, alphab,
                                                      viewsb, rgbW, rgbb, (float*)d_out);
}

// Round 15
// 396.346 us; speedup vs baseline: 1.3901x; 1.3901x over previous
//
#include <hip/hip_runtime.h>

#define N_PTS 131072
#define TILE 64
#define THREADS 512
#define REGION 40960   // per-head perm region (counts ~32.8K, >40 sigma headroom)

typedef __bf16 bf16;
typedef __bf16 bf16x8 __attribute__((ext_vector_type(8)));
typedef float f32x4 __attribute__((ext_vector_type(4)));

// ---------------- workspace layout (bytes) ----------------
#define WS_PERM_OFF   256                        // int perm[4][REGION]
#define WS_WPACK_OFF  (256 + 4 * REGION * 4)     // = 655616, bf16 packed weights
// packed-weight element offsets (bf16 elements, all [out][K] "transposed")
#define OFF_W0     0          // [256][64]   (k=63 zero pad)
#define OFF_WS     16384      // [3][256][256]
#define OFF_TW0    212992     // [4][256][320] (k: 0..62 pts, 63 zero, 64..319 h)
#define OFF_TWS    540672     // [12][256][256]
#define OFF_FEATW  1327104    // [4][256][256]
#define OFF_VIEWSW 1589248    // [4][128][288] (k: 0..255 feat, 256..282 views, 283..287 zero)
#define TOTAL_PACK 1736704

// ---------------- LDS layout (bytes) ----------------
// PTS [64][64]bf16 (8KB) + in-place H [64][256]bf16 (32KB)
// + B double-buffer 2 x 16KB = 72KB -> 2 blocks/CU at (512,4).
#define PTS_BASE 0
#define H_BASE   8192
#define B_BASE   40960
#define LDS_BYTES 73728

__device__ __forceinline__ unsigned swz(unsigned base, unsigned row, unsigned rowstride,
                                        unsigned kbyte) {
  return (base + row * rowstride + kbyte) ^ ((row & 7u) << 4);
}

// async global->LDS, 16B per lane; LDS dest = wave-uniform base + lane*16
__device__ __forceinline__ void gload_lds16(const bf16* g, char* l) {
  __builtin_amdgcn_global_load_lds(
      (const __attribute__((address_space(1))) void*)g,
      (__attribute__((address_space(3))) void*)l, 16, 0, 0);
}

// ================= weight pack (fp32->bf16 transpose) + head scatter =================
__global__ void k_pack(const float* __restrict__ W0, const float* __restrict__ Ws,
                       const float* __restrict__ tW0, const float* __restrict__ tWs,
                       const float* __restrict__ featW, const float* __restrict__ viewsW,
                       bf16* __restrict__ out, const int* __restrict__ head,
                       int* __restrict__ ctrl, int* __restrict__ perm) {
  int gid = blockIdx.x * blockDim.x + threadIdx.x;
  if (gid < N_PTS) {
    int h = head[gid];
    int lane = threadIdx.x & 63;
    #pragma unroll
    for (int hh = 0; hh < 4; ++hh) {
      unsigned long long m = __ballot(h == hh);
      if (m == 0ull) continue;
      int leader = __builtin_ctzll(m);
      int base = 0;
      if (lane == leader) base = atomicAdd(&ctrl[16 + hh], __popcll(m));
      base = __shfl(base, leader);
      if (h == hh) {
        int rank = __popcll(m & ((1ull << lane) - 1ull));
        perm[hh * REGION + base + rank] = gid;
      }
    }
  }

  for (int idx = gid; idx < TOTAL_PACK; idx += gridDim.x * blockDim.x) {
    float v;
    if (idx < OFF_WS) {
      int o = idx >> 6, k = idx & 63;
      v = (k < 63) ? W0[k * 256 + o] : 0.f;
    } else if (idx < OFF_TW0) {
      int i = idx - OFF_WS; int l = i >> 16, r = i & 65535, o = r >> 8, k = r & 255;
      v = Ws[l * 65536 + k * 256 + o];
    } else if (idx < OFF_TWS) {
      int i = idx - OFF_TW0; int h = i / 81920, r = i % 81920, o = r / 320, k = r % 320;
      v = (k < 63) ? tW0[(h * 319 + k) * 256 + o]
                   : (k == 63 ? 0.f : tW0[(h * 319 + k - 1) * 256 + o]);
    } else if (idx < OFF_FEATW) {
      int i = idx - OFF_TWS; int hj = i >> 16, r = i & 65535, o = r >> 8, k = r & 255;
      v = tWs[(hj * 256 + k) * 256 + o];
    } else if (idx < OFF_VIEWSW) {
      int i = idx - OFF_FEATW; int h = i >> 16, r = i & 65535, o = r >> 8, k = r & 255;
      v = featW[(h * 256 + k) * 256 + o];
    } else {
      int i = idx - OFF_VIEWSW; int h = i / 36864, r = i % 36864, o = r / 288, k = r % 288;
      v = (k < 283) ? viewsW[(h * 283 + k) * 128 + o] : 0.f;
    }
    out[idx] = (bf16)v;
  }
}

// ================= fused MLP layer (MFMA, strength-reduced addressing) =================
// 8 waves as 2 row-groups x 4 col-groups; wave tile = MR*16 x NF*16 (32x64).
// Sync skeleton = r12/r13's proven T3 2-phase: vmcnt(0) [stage(kc) had one
// full compute phase of slack] -> s_barrier -> stage(kc+1) -> reads -> MFMA.
//
// NEW (r15): all per-step address recomputation strength-reduced away.
// r13's spill (WRITE 57MB at (512,4)) and VALUBusy 29% were the ~120
// live addressing values per step from swz() recomputation. Now:
//  - A: row is FIXED per lane per m -> linear cursor a_cur (+64B/step) and
//    per-lane constant XOR a_xor; region switch = one uniform reset.
//    ((A+64)^X != (A^X)+64 when X overlaps bit 6, so XOR stays explicit.)
//  - B: per-lane constant base; buf flip = compile-time +16384 via
//    sub-step pairing (dostep(kc,0); dostep(kc+1,16384)) -> folds into the
//    ds_read immediate. Zero VALU.
//  - stage: global cursor += 32 elements/step; LDS dest = uniform constant.
// Arch demand ~50 + 32 acc fits (512,4)'s 128-reg budget honestly ->
// 2 blocks/CU AND spill-free, for the first time simultaneously.
template <int MR, int NF, bool RELU, int A0KC, int A1KC, int OUTS>
__device__ __forceinline__ void mfma_layer(char* lds, const bf16* __restrict__ Wt, int wK,
                                           const float* __restrict__ bias,
                                           int a0_base, int a0_stride,
                                           int a1_base, int a1_stride,
                                           int out_base, int out_stride,
                                           int lane, int wave) {
  const int l15 = lane & 15, l4 = lane >> 4;
  const int wr = wave >> 2, wc = wave & 3;
  constexpr int KC = A0KC + A1KC;
  constexpr int ISSUES = OUTS / 128;   // 2 (OUTS=256) or 1 (OUTS=128)
  f32x4 acc[MR][NF];
  #pragma unroll
  for (int m = 0; m < MR; ++m)
    #pragma unroll
    for (int n = 0; n < NF; ++n) acc[m][n] = (f32x4){0.f, 0.f, 0.f, 0.f};

  const int r0 = wr * (MR * 16);
  const int c0 = wc * (NF * 16);

  // B read bases: per-lane constants (buf0); buf1 = +16384 static offset
  const char* bbase[NF];
  #pragma unroll
  for (int n = 0; n < NF; ++n) {
    int col = c0 + n * 16 + l15;
    bbase[n] = lds + B_BASE + col * 64 + ((l4 ^ ((col >> 1) & 3)) << 4);
  }

  // A cursors: pre-XOR linear byte offset (advances 64/step) + per-lane XOR
  unsigned a_cur[MR], a_xor[MR];
  #pragma unroll
  for (int m = 0; m < MR; ++m) {
    int row = r0 + m * 16 + l15;
    a_cur[m] = a0_base + row * a0_stride + l4 * 16;
    a_xor[m] = (row & 7u) << 4;
  }

  // stage cursors: per-lane global src (advances 32 elem/step)
  const bf16* gsrc[ISSUES];
  #pragma unroll
  for (int s = 0; s < ISSUES; ++s) {
    int reg = wave * ISSUES + s;
    int o = reg * 16 + (lane >> 2);
    int j = lane & 3;
    gsrc[s] = Wt + o * wK + ((j ^ ((o >> 1) & 3)) << 3);
  }

  // prologue: stage buf0 (kc=0)
  #pragma unroll
  for (int s = 0; s < ISSUES; ++s) {
    gload_lds16(gsrc[s], lds + B_BASE + (wave * ISSUES + s) * 1024);
    gsrc[s] += 32;
  }

  auto dostep = [&](int kc, int bufoff) {
    asm volatile("s_waitcnt vmcnt(0)" ::: "memory");  // stage(kc) landed
    __builtin_amdgcn_s_barrier();

    if (kc + 1 < KC) {
      #pragma unroll
      for (int s = 0; s < ISSUES; ++s) {
        gload_lds16(gsrc[s], lds + B_BASE + (bufoff ^ 16384) + (wave * ISSUES + s) * 1024);
        gsrc[s] += 32;
      }
    }
    if (A1KC > 0 && kc == A0KC) {   // one-time region switch (uniform branch)
      #pragma unroll
      for (int m = 0; m < MR; ++m)
        a_cur[m] = a1_base + (r0 + m * 16 + l15) * a1_stride + l4 * 16;
    }

    bf16x8 a[MR], b[NF];
    #pragma unroll
    for (int m = 0; m < MR; ++m) {
      a[m] = *(const bf16x8*)(lds + (a_cur[m] ^ a_xor[m]));
      a_cur[m] += 64;
    }
    #pragma unroll
    for (int n = 0; n < NF; ++n)
      b[n] = *(const bf16x8*)(bbase[n] + bufoff);

    __builtin_amdgcn_s_setprio(1);
    #pragma unroll
    for (int n = 0; n < NF; ++n)
      #pragma unroll
      for (int m = 0; m < MR; ++m)
        acc[m][n] = __builtin_amdgcn_mfma_f32_16x16x32_bf16(a[m], b[n], acc[m][n], 0, 0, 0);
    __builtin_amdgcn_s_setprio(0);
  };

  #pragma unroll 1
  for (int kc = 0; kc + 1 < KC; kc += 2) {
    dostep(kc, 0);
    dostep(kc + 1, 16384);
  }
  if (KC & 1) dostep(KC - 1, 0);   // odd tail (KC=9: kc=8 -> buf0)

  // all waves' A-reads complete (reads retire before their MFMAs, which
  // precede this barrier) -> in-place overwrite of the A region is safe
  __builtin_amdgcn_s_barrier();

  #pragma unroll
  for (int n = 0; n < NF; ++n) {
    int col = c0 + n * 16 + l15;
    float bv = bias[col];
    #pragma unroll
    for (int m = 0; m < MR; ++m) {
      #pragma unroll
      for (int j = 0; j < 4; ++j) {
        float v = acc[m][n][j] + bv;
        if (RELU) v = fmaxf(v, 0.f);
        int row = r0 + m * 16 + l4 * 4 + j;
        *(bf16*)(lds + swz(out_base, row, out_stride, col * 2)) = (bf16)v;
      }
    }
  }
  __syncthreads();  // full drain: epilogue visible to next layer
}

// ================= main fused kernel =================
// (512,4): 128-reg budget -> 16 waves/CU (2 blocks). Demand now ~50 arch
// + 32 acc (strength-reduced addressing) -> fits honestly, no spill.
__global__ __launch_bounds__(THREADS, 4) void k_main(
    const float* __restrict__ x, const int* __restrict__ ctrl, const int* __restrict__ perm,
    const bf16* __restrict__ wpack,
    const float* __restrict__ b0, const float* __restrict__ bs,
    const float* __restrict__ tb0p, const float* __restrict__ tbsp,
    const float* __restrict__ featb, const float* __restrict__ alphaW,
    const float* __restrict__ alphab, const float* __restrict__ viewsb,
    const float* __restrict__ rgbW, const float* __restrict__ rgbb,
    float* __restrict__ outp) {
  __shared__ __attribute__((aligned(16))) char lds[LDS_BYTES];
  __shared__ int pidx[TILE];
  __shared__ float alpha_s[TILE];

  const int tid = threadIdx.x;
  const int lane = tid & 63, wave = tid >> 6;

  // ---- fixed-grid head/tile mapping: block -> (head, tile) ----
  const int hh = blockIdx.x / (REGION / TILE);
  const int start = (blockIdx.x % (REGION / TILE)) * TILE;
  const int cnt = ctrl[16 + hh];
  if (start >= cnt) return;            // empty tile (uniform exit)
  const int nv = min(TILE, cnt - start);

  if (tid < TILE) pidx[tid] = (tid < nv) ? perm[hh * REGION + start + tid] : -1;
  __syncthreads();

  // ---- pts -> LDS bf16 [64][64] (col 63 = 0, rows>=nv = 0) ----
  for (int i = tid; i < TILE * 64; i += THREADS) {
    int row = i >> 6, c = i & 63;
    int p = pidx[row];
    float v = (p >= 0 && c < 63) ? x[p * 90 + c] : 0.f;
    *(bf16*)(lds + swz(PTS_BASE, row, 128, c * 2)) = (bf16)v;
  }
  __syncthreads();  // pts visible before W0's raw-barrier loop reads them

  const bf16* W0p    = wpack + OFF_W0;
  const bf16* Wsp    = wpack + OFF_WS;
  const bf16* tW0p   = wpack + OFF_TW0 + hh * 81920;
  const bf16* tWsp   = wpack + OFF_TWS + hh * 3 * 65536;
  const bf16* featWp = wpack + OFF_FEATW + hh * 65536;
  const bf16* viewsWp= wpack + OFF_VIEWSW + hh * 36864;

  // trunk: 63->256, 3x 256->256 (in-place H)
  mfma_layer<2, 4, true, 2, 0, 256>(lds, W0p, 64, b0, PTS_BASE, 128, 0, 0, H_BASE, 512, lane, wave);
  mfma_layer<2, 4, true, 8, 0, 256>(lds, Wsp,          256, bs,       H_BASE, 512, 0, 0, H_BASE, 512, lane, wave);
  mfma_layer<2, 4, true, 8, 0, 256>(lds, Wsp + 65536,  256, bs + 256, H_BASE, 512, 0, 0, H_BASE, 512, lane, wave);
  mfma_layer<2, 4, true, 8, 0, 256>(lds, Wsp + 131072, 256, bs + 512, H_BASE, 512, 0, 0, H_BASE, 512, lane, wave);
  // T0: concat(pts, h) 320 -> 256
  mfma_layer<2, 4, true, 2, 8, 256>(lds, tW0p, 320, tb0p + hh * 256,
                                    PTS_BASE, 128, H_BASE, 512, H_BASE, 512, lane, wave);

  // views -> PTS cols 0..31 (T0's PTS reads complete before its epilogue barrier)
  for (int i = tid; i < TILE * 32; i += THREADS) {
    int row = i >> 5, c = i & 31;
    int p = pidx[row];
    float v = (p >= 0 && c < 27) ? x[p * 90 + 63 + c] : 0.f;
    *(bf16*)(lds + swz(PTS_BASE, row, 128, c * 2)) = (bf16)v;
  }
  __syncthreads();  // views-gather writes drained before later raw-barrier layers

  // head layers
  mfma_layer<2, 4, true, 8, 0, 256>(lds, tWsp,          256, tbsp + hh * 768,       H_BASE, 512, 0, 0, H_BASE, 512, lane, wave);
  mfma_layer<2, 4, true, 8, 0, 256>(lds, tWsp + 65536,  256, tbsp + hh * 768 + 256, H_BASE, 512, 0, 0, H_BASE, 512, lane, wave);
  mfma_layer<2, 4, true, 8, 0, 256>(lds, tWsp + 131072, 256, tbsp + hh * 768 + 512, H_BASE, 512, 0, 0, H_BASE, 512, lane, wave);

  // ---- alpha = ha . alphaW[hh] + alphab (waves 0-3; completes before feat's
  //      epilogue because all waves must pass feat's kc barriers first) ----
  if (wave < 4) {
    int p = wave * 16 + (lane & 15);
    int kq = lane >> 4;
    const float* aW = alphaW + hh * 256;
    float s = 0.f;
    for (int i = 0; i < 8; ++i) {
      int k = kq * 64 + i * 8;
      bf16x8 hv8 = *(const bf16x8*)(lds + swz(H_BASE, p, 512, k * 2));
      #pragma unroll
      for (int j = 0; j < 8; ++j) s += (float)hv8[j] * aW[k + j];
    }
    s += __shfl_xor(s, 16);
    s += __shfl_xor(s, 32);
    if (kq == 0) alpha_s[p] = s + alphab[hh];
  }

  // feat: 256->256 in-place, NO relu
  mfma_layer<2, 4, false, 8, 0, 256>(lds, featWp, 256, featb + hh * 256,
                                     H_BASE, 512, 0, 0, H_BASE, 512, lane, wave);
  // views: concat(feat, views[32pad]) 288 -> 128, relu, into H cols 0..127
  mfma_layer<2, 2, true, 8, 1, 128>(lds, viewsWp, 288, viewsb + hh * 128,
                                    H_BASE, 512, PTS_BASE, 128, H_BASE, 512, lane, wave);

  // ---- rgb = hv . rgbW[hh] + rgbb ; write float4 {r,g,b,alpha} (waves 0-3) ----
  if (wave < 4) {
    int p = wave * 16 + (lane & 15);
    int kq = lane >> 4;
    const float* rW = rgbW + hh * 128 * 3;
    float r0 = 0.f, r1 = 0.f, r2 = 0.f;
    for (int i = 0; i < 4; ++i) {
      int k = kq * 32 + i * 8;
      bf16x8 hv8 = *(const bf16x8*)(lds + swz(H_BASE, p, 512, k * 2));
      #pragma unroll
      for (int j = 0; j < 8; ++j) {
        float hvf = (float)hv8[j];
        r0 += hvf * rW[(k + j) * 3 + 0];
        r1 += hvf * rW[(k + j) * 3 + 1];
        r2 += hvf * rW[(k + j) * 3 + 2];
      }
    }
    r0 += __shfl_xor(r0, 16); r0 += __shfl_xor(r0, 32);
    r1 += __shfl_xor(r1, 16); r1 += __shfl_xor(r1, 32);
    r2 += __shfl_xor(r2, 16); r2 += __shfl_xor(r2, 32);
    if (kq == 0 && p < nv) {
      int pt = pidx[p];
      float4 o = make_float4(r0 + rgbb[hh * 3 + 0], r1 + rgbb[hh * 3 + 1],
                             r2 + rgbb[hh * 3 + 2], alpha_s[p]);
      *(float4*)(outp + pt * 4) = o;
    }
  }
}

// ================= launch =================
extern "C" void kernel_launch(void* const* d_in, const int* in_sizes, int n_in,
                              void* d_out, int out_size, void* d_ws, size_t ws_size,
                              hipStream_t stream) {
  const float* x      = (const float*)d_in[0];
  const int*   head   = (const int*)d_in[1];
  const float* W0     = (const float*)d_in[2];
  const float* b0     = (const float*)d_in[3];
  const float* Ws     = (const float*)d_in[4];
  const float* bs     = (const float*)d_in[5];
  const float* tW0    = (const float*)d_in[6];
  const float* tb0    = (const float*)d_in[7];
  const float* tWs    = (const float*)d_in[8];
  const float* tbs    = (const float*)d_in[9];
  const float* featW  = (const float*)d_in[10];
  const float* featb  = (const float*)d_in[11];
  const float* alphaW = (const float*)d_in[12];
  const float* alphab = (const float*)d_in[13];
  const float* viewsW = (const float*)d_in[14];
  const float* viewsb = (const float*)d_in[15];
  const float* rgbW   = (const float*)d_in[16];
  const float* rgbb   = (const float*)d_in[17];

  int*  ctrl  = (int*)d_ws;
  int*  perm  = (int*)((char*)d_ws + WS_PERM_OFF);
  bf16* wpack = (bf16*)((char*)d_ws + WS_WPACK_OFF);

  hipMemsetAsync(ctrl, 0, 256, stream);
  k_pack<<<2048, 256, 0, stream>>>(W0, Ws, tW0, tWs, featW, viewsW, wpack, head, ctrl, perm);
  k_main<<<4 * (REGION / TILE), THREADS, 0, stream>>>(x, ctrl, perm, wpack,
                                                      b0, bs, tb0, tbs, featb, alphaW, alphab,
                                                      viewsb, rgbW, rgbb, (float*)d_out);
}

// Round 16
// 392.780 us; speedup vs baseline: 1.4028x; 1.0091x over previous
//
#include <hip/hip_runtime.h>

#define N_PTS 131072
#define TILE 64
#define THREADS 512
#define REGION 40960   // per-head perm region (counts ~32.8K, >40 sigma headroom)

typedef __bf16 bf16;
typedef __bf16 bf16x8 __attribute__((ext_vector_type(8)));
typedef float f32x4 __attribute__((ext_vector_type(4)));

// ---------------- workspace layout (bytes) ----------------
#define WS_PERM_OFF   256                        // int perm[4][REGION]
#define WS_WPACK_OFF  (256 + 4 * REGION * 4)     // bf16 packed weights
// packed-weight element offsets (bf16 elements, all [out][K] "transposed")
#define OFF_W0     0          // [256][64]   (k=63 zero pad)
#define OFF_WS     16384      // [3][256][256]
#define OFF_TW0    212992     // [4][256][320] (k: 0..62 pts, 63 zero, 64..319 h)
#define OFF_TWS    540672     // [12][256][256]
#define OFF_FEATW  1327104    // [4][256][256]
#define OFF_VIEWSW 1589248    // [4][128][288] (k: 0..255 feat, 256..282 views, 283..287 zero)
#define TOTAL_PACK 1736704

// ---------------- LDS layout (bytes) ----------------
// H [64][256] bf16 (32KB, base 0) + B ring-3 x 16KB (48KB) = 80KB exactly
// -> 2 blocks/CU. PTS buffer eliminated (pts/views live in registers) to
// fund the ring-3 needed for counted-vmcnt (T4: never drain to 0 in-loop).
#define H_BASE 0
#define B_BASE 32768
#define LDS_BYTES 81920

__device__ __forceinline__ unsigned swz(unsigned base, unsigned row, unsigned rowstride,
                                        unsigned kbyte) {
  return (base + row * rowstride + kbyte) ^ ((row & 7u) << 4);
}

// async global->LDS, 16B per lane; LDS dest = wave-uniform base + lane*16
__device__ __forceinline__ void gload_lds16(const bf16* g, char* l) {
  __builtin_amdgcn_global_load_lds(
      (const __attribute__((address_space(1))) void*)g,
      (__attribute__((address_space(3))) void*)l, 16, 0, 0);
}

template <int N>
__device__ __forceinline__ void wait_stage() {
  if constexpr (N == 0)      asm volatile("s_waitcnt vmcnt(0)" ::: "memory");
  else if constexpr (N == 1) asm volatile("s_waitcnt vmcnt(1)" ::: "memory");
  else                       asm volatile("s_waitcnt vmcnt(2)" ::: "memory");
}

// ================= weight pack (k-major: coalesced reads) + head scatter ==========
// r15's o-major enumeration read the fp32 sources with stride-1KB lanes
// (uncoalesced, ~16x over-fetch). k-major reads are contiguous; the 2B
// scattered writes are fire-and-forget.
__global__ void k_pack(const float* __restrict__ W0, const float* __restrict__ Ws,
                       const float* __restrict__ tW0, const float* __restrict__ tWs,
                       const float* __restrict__ featW, const float* __restrict__ viewsW,
                       bf16* __restrict__ out, const int* __restrict__ head,
                       int* __restrict__ ctrl, int* __restrict__ perm) {
  int gid = blockIdx.x * blockDim.x + threadIdx.x;
  if (gid < N_PTS) {
    int h = head[gid];
    int lane = threadIdx.x & 63;
    #pragma unroll
    for (int hh = 0; hh < 4; ++hh) {
      unsigned long long m = __ballot(h == hh);
      if (m == 0ull) continue;
      int leader = __builtin_ctzll(m);
      int base = 0;
      if (lane == leader) base = atomicAdd(&ctrl[16 + hh], __popcll(m));
      base = __shfl(base, leader);
      if (h == hh) {
        int rank = __popcll(m & ((1ull << lane) - 1ull));
        perm[hh * REGION + base + rank] = gid;
      }
    }
  }

  for (int idx = gid; idx < TOTAL_PACK; idx += gridDim.x * blockDim.x) {
    float v; int dst;
    if (idx < 16384) {                                   // W0: 64k x 256o
      int k = idx >> 8, o = idx & 255;
      v = (k < 63) ? W0[k * 256 + o] : 0.f;
      dst = OFF_W0 + o * 64 + k;
    } else if (idx < 212992) {                           // Ws: 3 x 256k x 256o
      int i = idx - 16384; int l = i >> 16, r = i & 65535, k = r >> 8, o = r & 255;
      v = Ws[i];
      dst = OFF_WS + l * 65536 + o * 256 + k;
    } else if (idx < 540672) {                           // tW0: 4 x 320k x 256o
      int i = idx - 212992; int h = i / 81920, r = i % 81920, k = r >> 8, o = r & 255;
      v = (k < 63) ? tW0[(h * 319 + k) * 256 + o]
                   : (k == 63 ? 0.f : tW0[(h * 319 + k - 1) * 256 + o]);
      dst = OFF_TW0 + h * 81920 + o * 320 + k;
    } else if (idx < 1327104) {                          // tWs: 12 x 256k x 256o
      int i = idx - 540672; int hj = i >> 16, r = i & 65535, k = r >> 8, o = r & 255;
      v = tWs[i];
      dst = OFF_TWS + hj * 65536 + o * 256 + k;
    } else if (idx < 1589248) {                          // featW: 4 x 256k x 256o
      int i = idx - 1327104; int h = i >> 16, r = i & 65535, k = r >> 8, o = r & 255;
      v = featW[i];
      dst = OFF_FEATW + h * 65536 + o * 256 + k;
    } else {                                             // viewsW: 4 x 288k x 128o
      int i = idx - 1589248; int h = i / 36864, r = i % 36864, k = r >> 7, o = r & 127;
      v = (k < 283) ? viewsW[(h * 283 + k) * 128 + o] : 0.f;
      dst = OFF_VIEWSW + h * 36864 + o * 288 + k;
    }
    out[dst] = (bf16)v;
  }
}

// ================= fused MLP layer: ring-3 B, counted vmcnt (T3+T4) ==============
// 8 waves = 2 row-groups x 4 col-groups; wave tile = MR*16 x NF*16.
// Pipeline: prologue stages buf0,buf1; per step kc:
//   s_waitcnt vmcnt(ISSUES)   <- drains stage(kc) ONLY; stage(kc+1) stays
//                                in flight ACROSS the barrier (T4)
//   s_barrier
//   stage(kc+2) -> buf[(kc+2)%3]   (WAR-safe: its readers finished step kc-1)
//   ds_read A (cursor+XOR, m*8192 imm) / reg-frag A; ds_read B (base + ring
//   scalar + n*1024 imm); setprio(1); MR*NF MFMA; setprio(0)
// Last step waits vmcnt(0). A-operand may come from registers (RKC static
// steps holding pts/views fragments) - this freed the PTS LDS buffer.
#define PIPE_STEP(WAITN, DO_STAGE, LOAD_A)                                     \
  do {                                                                         \
    wait_stage<WAITN>();                                                       \
    __builtin_amdgcn_s_barrier();                                              \
    if (DO_STAGE) {                                                            \
      _Pragma("unroll")                                                        \
      for (int s = 0; s < ISSUES; ++s) {                                       \
        gload_lds16(gsrc[s], sbase + sd + s * 1024);                           \
        gsrc[s] += 32;                                                         \
      }                                                                        \
      sd = (sd == 32768) ? 0 : sd + 16384;                                     \
    }                                                                          \
    bf16x8 a[MR];                                                              \
    LOAD_A;                                                                    \
    bf16x8 b[NF];                                                              \
    {                                                                          \
      const char* bp = lds + breg + sr;                                        \
      _Pragma("unroll")                                                        \
      for (int n = 0; n < NF; ++n) b[n] = *(const bf16x8*)(bp + n * 1024);     \
    }                                                                          \
    sr = (sr == 32768) ? 0 : sr + 16384;                                       \
    __builtin_amdgcn_s_setprio(1);                                             \
    _Pragma("unroll")                                                          \
    for (int n = 0; n < NF; ++n)                                               \
      _Pragma("unroll")                                                        \
      for (int m = 0; m < MR; ++m)                                             \
        acc[m][n] =                                                            \
            __builtin_amdgcn_mfma_f32_16x16x32_bf16(a[m], b[n], acc[m][n],     \
                                                    0, 0, 0);                  \
    __builtin_amdgcn_s_setprio(0);                                             \
  } while (0)

#define LOADA_REG(K)                                                           \
  { _Pragma("unroll") for (int m = 0; m < MR; ++m) a[m] = aregs[(K) * MR + m]; }

#define LOADA_LDS                                                              \
  {                                                                            \
    unsigned va = acur ^ axor;                                                 \
    _Pragma("unroll")                                                          \
    for (int m = 0; m < MR; ++m) a[m] = *(const bf16x8*)(lds + va + m * 8192); \
    acur += 64;                                                                \
  }

template <int MR, int NF, bool RELU, int RKC, int LKC, bool REG_FIRST, int OUTS>
__device__ __forceinline__ void mfma_layer(char* lds, const bf16* __restrict__ Wt,
                                           int wK, const float* __restrict__ bias,
                                           const bf16x8* aregs,
                                           int lane, int wave) {
  const int l15 = lane & 15, l4 = lane >> 4;
  const int wr = wave >> 2, wc = wave & 3;
  constexpr int KC = RKC + LKC;
  constexpr int ISSUES = OUTS / 128;   // 2 (OUTS=256) or 1 (OUTS=128)
  f32x4 acc[MR][NF];
  #pragma unroll
  for (int m = 0; m < MR; ++m)
    #pragma unroll
    for (int n = 0; n < NF; ++n) acc[m][n] = (f32x4){0.f, 0.f, 0.f, 0.f};

  const int r0 = wr * (MR * 16);
  const int c0 = wc * (NF * 16);

  // B vaddr base: slot = l4 ^ ((col>>1)&3) == l4 ^ ((l15>>1)&3) for all n
  // (n*1024 and ring offset folded into immediates / one scalar add)
  const int breg = B_BASE + (c0 + l15) * 64 + ((l4 ^ ((l15 >> 1) & 3)) << 4);

  // A (LDS/H) cursor: +64B per LDS step; XOR swizzle separate; m via 8192 imm
  unsigned acur = (unsigned)((r0 + l15) * 512 + l4 * 16);
  const unsigned axor = (l15 & 7u) << 4;

  // stage source cursors (per-lane; advance 32 elements per step)
  const bf16* gsrc[ISSUES];
  #pragma unroll
  for (int s = 0; s < ISSUES; ++s) {
    int reg = wave * ISSUES + s;
    int o = reg * 16 + (lane >> 2);
    int j = lane & 3;
    gsrc[s] = Wt + o * wK + ((j ^ ((o >> 1) & 3)) << 3);
  }
  char* sbase = lds + B_BASE + (wave * ISSUES) * 1024;

  // prologue: stage buf0, buf1
  #pragma unroll
  for (int s = 0; s < ISSUES; ++s) { gload_lds16(gsrc[s], sbase + s * 1024); gsrc[s] += 32; }
  #pragma unroll
  for (int s = 0; s < ISSUES; ++s) { gload_lds16(gsrc[s], sbase + 16384 + s * 1024); gsrc[s] += 32; }

  int sr = 0;       // ring read offset  (kc%3 * 16384)
  int sd = 32768;   // ring stage-dest offset ((kc+2)%3 * 16384)

  // ---- phase 1: leading register-A steps (static indices) ----
  if constexpr (REG_FIRST && RKC >= 1) {
    if constexpr (KC == 1) PIPE_STEP(0, false, LOADA_REG(0));
    else                   PIPE_STEP(ISSUES, (2 < KC), LOADA_REG(0));
  }
  if constexpr (REG_FIRST && RKC >= 2) {
    if constexpr (KC == 2) PIPE_STEP(0, false, LOADA_REG(1));
    else                   PIPE_STEP(ISSUES, (3 < KC), LOADA_REG(1));
  }

  // ---- phase 2: LDS-A steps ----
  if constexpr (LKC > 0) {
    constexpr int kc0 = REG_FIRST ? RKC : 0;
    constexpr bool last_in_lds = (REG_FIRST || RKC == 0);
    constexpr int kcend = REG_FIRST ? KC : LKC;
    constexpr int loop_end = kcend - (last_in_lds ? 1 : 0);
    #pragma unroll 1
    for (int kc = kc0; kc < loop_end; ++kc) {
      PIPE_STEP(ISSUES, (kc + 2 < KC), LOADA_LDS);
    }
    if constexpr (last_in_lds) PIPE_STEP(0, false, LOADA_LDS);
  }

  // ---- phase 3: trailing register-A step (views) ----
  if constexpr (!REG_FIRST && RKC >= 1) {
    PIPE_STEP(0, false, LOADA_REG(0));
  }

  // all waves' A-reads complete (reads retire before their MFMAs, which
  // precede the final step's barrier... add one more to be explicit)
  __builtin_amdgcn_s_barrier();

  #pragma unroll
  for (int n = 0; n < NF; ++n) {
    int col = c0 + n * 16 + l15;
    float bv = bias[col];
    #pragma unroll
    for (int m = 0; m < MR; ++m) {
      #pragma unroll
      for (int j = 0; j < 4; ++j) {
        float v = acc[m][n][j] + bv;
        if (RELU) v = fmaxf(v, 0.f);
        int row = r0 + m * 16 + l4 * 4 + j;
        *(bf16*)(lds + swz(H_BASE, row, 512, col * 2)) = (bf16)v;
      }
    }
  }
  __syncthreads();  // full drain: epilogue visible to next layer
}

// ================= main fused kernel =================
__global__ __launch_bounds__(THREADS, 4) void k_main(
    const float* __restrict__ x, const int* __restrict__ ctrl, const int* __restrict__ perm,
    const bf16* __restrict__ wpack,
    const float* __restrict__ b0, const float* __restrict__ bs,
    const float* __restrict__ tb0p, const float* __restrict__ tbsp,
    const float* __restrict__ featb, const float* __restrict__ alphaW,
    const float* __restrict__ alphab, const float* __restrict__ viewsb,
    const float* __restrict__ rgbW, const float* __restrict__ rgbb,
    float* __restrict__ outp) {
  __shared__ __attribute__((aligned(16))) char lds[LDS_BYTES];

  const int tid = threadIdx.x;
  const int lane = tid & 63, wave = tid >> 6;
  const int l15 = lane & 15, l4 = lane >> 4;

  // ---- fixed-grid head/tile mapping ----
  const int hh = blockIdx.x / (REGION / TILE);
  const int start = (blockIdx.x % (REGION / TILE)) * TILE;
  const int cnt = ctrl[16 + hh];
  if (start >= cnt) return;            // empty tile (uniform exit)
  const int nv = min(TILE, cnt - start);
  const int permbase = hh * REGION + start;

  // ---- pts/views fragments -> registers (one-time gather; replaces the
  //      PTS LDS buffer; rows >= nv zeroed) ----
  bf16x8 ptsreg[4];    // [rkc*2+m]: row = wr*32+m*16+l15, k = rkc*32+l4*8+j (k=63 -> 0)
  bf16x8 viewsreg[2];  // [m]:       row same,             k = l4*8+j (k>=27 -> 0)
  {
    const int wr = wave >> 2;
    #pragma unroll
    for (int m = 0; m < 2; ++m) {
      int row = wr * 32 + m * 16 + l15;
      bool valid = (start + row) < cnt;
      int p = valid ? perm[permbase + row] : 0;
      const float* xr = x + p * 90;
      #pragma unroll
      for (int rkc = 0; rkc < 2; ++rkc) {
        int k0 = rkc * 32 + l4 * 8;
        bf16x8 f;
        #pragma unroll
        for (int j = 0; j < 8; ++j) {
          int k = k0 + j;
          f[j] = (bf16)((valid && k < 63) ? xr[k] : 0.f);
        }
        ptsreg[rkc * 2 + m] = f;
      }
      {
        int k0 = l4 * 8;
        bf16x8 f;
        #pragma unroll
        for (int j = 0; j < 8; ++j) {
          int k = k0 + j;
          f[j] = (bf16)((valid && k < 27) ? xr[63 + k] : 0.f);
        }
        viewsreg[m] = f;
      }
    }
  }

  const bf16* W0p    = wpack + OFF_W0;
  const bf16* Wsp    = wpack + OFF_WS;
  const bf16* tW0p   = wpack + OFF_TW0 + hh * 81920;
  const bf16* tWsp   = wpack + OFF_TWS + hh * 3 * 65536;
  const bf16* featWp = wpack + OFF_FEATW + hh * 65536;
  const bf16* viewsWp= wpack + OFF_VIEWSW + hh * 36864;

  // trunk: W0 (A entirely from regs), 3x 256->256 (A from H)
  mfma_layer<2, 4, true, 2, 0, true,  256>(lds, W0p, 64, b0, ptsreg, lane, wave);
  mfma_layer<2, 4, true, 0, 8, false, 256>(lds, Wsp,          256, bs,       nullptr, lane, wave);
  mfma_layer<2, 4, true, 0, 8, false, 256>(lds, Wsp + 65536,  256, bs + 256, nullptr, lane, wave);
  mfma_layer<2, 4, true, 0, 8, false, 256>(lds, Wsp + 131072, 256, bs + 512, nullptr, lane, wave);
  // T0: concat(pts[regs], h[LDS]) 320 -> 256
  mfma_layer<2, 4, true, 2, 8, true,  256>(lds, tW0p, 320, tb0p + hh * 256, ptsreg, lane, wave);

  // head layers
  mfma_layer<2, 4, true, 0, 8, false, 256>(lds, tWsp,          256, tbsp + hh * 768,       nullptr, lane, wave);
  mfma_layer<2, 4, true, 0, 8, false, 256>(lds, tWsp + 65536,  256, tbsp + hh * 768 + 256, nullptr, lane, wave);
  mfma_layer<2, 4, true, 0, 8, false, 256>(lds, tWsp + 131072, 256, tbsp + hh * 768 + 512, nullptr, lane, wave);

  // ---- alpha = ha . alphaW[hh] + alphab (waves 0-3, kept in a register;
  //      completes before feat's in-place epilogue: all waves must pass
  //      feat's kc barriers first) ----
  float my_alpha = 0.f;
  if (wave < 4) {
    int p = wave * 16 + l15;
    int kq = l4 >> 1;  // 0 or 1 halves? -> use l4 split below
    const float* aW = alphaW + hh * 256;
    float s = 0.f;
    int kqq = lane >> 4;  // 0..3
    for (int i = 0; i < 4; ++i) {
      int k = kqq * 64 + i * 16;
      // read 16 bf16 = 2x bf16x8
      bf16x8 h0 = *(const bf16x8*)(lds + swz(H_BASE, p, 512, k * 2));
      bf16x8 h1 = *(const bf16x8*)(lds + swz(H_BASE, p, 512, (k + 8) * 2));
      #pragma unroll
      for (int j = 0; j < 8; ++j) s += (float)h0[j] * aW[k + j];
      #pragma unroll
      for (int j = 0; j < 8; ++j) s += (float)h1[j] * aW[k + 8 + j];
    }
    s += __shfl_xor(s, 16);
    s += __shfl_xor(s, 32);
    my_alpha = s + alphab[hh];
    (void)kq;
  }

  // feat: 256->256 in-place, NO relu
  mfma_layer<2, 4, false, 0, 8, false, 256>(lds, featWp, 256, featb + hh * 256, nullptr, lane, wave);
  // views: concat(feat[LDS], views[regs]) 288 -> 128, relu, into H cols 0..127
  mfma_layer<2, 2, true, 1, 8, false, 128>(lds, viewsWp, 288, viewsb + hh * 128, viewsreg, lane, wave);

  // ---- rgb = hv . rgbW[hh] + rgbb ; write float4 {r,g,b,alpha} (waves 0-3) ----
  if (wave < 4) {
    int p = wave * 16 + l15;
    int kq = lane >> 4;
    const float* rW = rgbW + hh * 128 * 3;
    float r0 = 0.f, r1 = 0.f, r2 = 0.f;
    for (int i = 0; i < 4; ++i) {
      int k = kq * 32 + i * 8;
      bf16x8 hv8 = *(const bf16x8*)(lds + swz(H_BASE, p, 512, k * 2));
      #pragma unroll
      for (int j = 0; j < 8; ++j) {
        float hvf = (float)hv8[j];
        r0 += hvf * rW[(k + j) * 3 + 0];
        r1 += hvf * rW[(k + j) * 3 + 1];
        r2 += hvf * rW[(k + j) * 3 + 2];
      }
    }
    r0 += __shfl_xor(r0, 16); r0 += __shfl_xor(r0, 32);
    r1 += __shfl_xor(r1, 16); r1 += __shfl_xor(r1, 32);
    r2 += __shfl_xor(r2, 16); r2 += __shfl_xor(r2, 32);
    if (kq == 0 && p < nv) {
      int pt = perm[permbase + p];
      float4 o = make_float4(r0 + rgbb[hh * 3 + 0], r1 + rgbb[hh * 3 + 1],
                             r2 + rgbb[hh * 3 + 2], my_alpha);
      *(float4*)(outp + pt * 4) = o;
    }
  }
}

// ================= launch =================
extern "C" void kernel_launch(void* const* d_in, const int* in_sizes, int n_in,
                              void* d_out, int out_size, void* d_ws, size_t ws_size,
                              hipStream_t stream) {
  const float* x      = (const float*)d_in[0];
  const int*   head   = (const int*)d_in[1];
  const float* W0     = (const float*)d_in[2];
  const float* b0     = (const float*)d_in[3];
  const float* Ws     = (const float*)d_in[4];
  const float* bs     = (const float*)d_in[5];
  const float* tW0    = (const float*)d_in[6];
  const float* tb0    = (const float*)d_in[7];
  const float* tWs    = (const float*)d_in[8];
  const float* tbs    = (const float*)d_in[9];
  const float* featW  = (const float*)d_in[10];
  const float* featb  = (const float*)d_in[11];
  const float* alphaW = (const float*)d_in[12];
  const float* alphab = (const float*)d_in[13];
  const float* viewsW = (const float*)d_in[14];
  const float* viewsb = (const float*)d_in[15];
  const float* rgbW   = (const float*)d_in[16];
  const float* rgbb   = (const float*)d_in[17];

  int*  ctrl  = (int*)d_ws;
  int*  perm  = (int*)((char*)d_ws + WS_PERM_OFF);
  bf16* wpack = (bf16*)((char*)d_ws + WS_WPACK_OFF);

  hipMemsetAsync(ctrl, 0, 256, stream);
  k_pack<<<2048, 256, 0, stream>>>(W0, Ws, tW0, tWs, featW, viewsW, wpack, head, ctrl, perm);
  k_main<<<4 * (REGION / TILE), THREADS, 0, stream>>>(x, ctrl, perm, wpack,
                                                      b0, bs, tb0, tbs, featb, alphaW, alphab,
                                                      viewsb, rgbW, rgbb, (float*)d_out);
}